// Round 3
// baseline (596.833 us; speedup 1.0000x reference)
//
#include <hip/hip_runtime.h>
#include <stdint.h>

typedef unsigned short u16;
typedef __attribute__((ext_vector_type(8))) u16 u16x8;
typedef __attribute__((ext_vector_type(8))) __bf16 bf16x8;
typedef __attribute__((ext_vector_type(4))) float f32x4;

#define L2E 1.4426950408889634f

__device__ __forceinline__ float bf2f(u16 u) {
  union { unsigned i; float f; } v; v.i = ((unsigned)u) << 16; return v.f;
}
__device__ __forceinline__ u16 f2bf_rne(float f) {
  union { float f; unsigned u; } v; v.f = f;
  const unsigned r = v.u + 0x7FFFu + ((v.u >> 16) & 1u);
  return (u16)(r >> 16);
}
__device__ __forceinline__ bf16x8 ldb(const u16* p) {
  u16x8 v = *reinterpret_cast<const u16x8*>(p);
  return __builtin_bit_cast(bf16x8, v);
}
// fp32 -> split bf16 via truncation: f = hi + lo + O(2^-16 |f|)
__device__ __forceinline__ void split8t(const float* p, bf16x8& h, bf16x8& l) {
  const float4 v0 = *reinterpret_cast<const float4*>(p);
  const float4 v1 = *reinterpret_cast<const float4*>(p + 4);
  const float f[8] = {v0.x, v0.y, v0.z, v0.w, v1.x, v1.y, v1.z, v1.w};
  u16x8 hu, lu;
#pragma unroll
  for (int i = 0; i < 8; ++i) {
    union { float f; unsigned u; } a; a.f = f[i];
    hu[i] = (u16)(a.u >> 16);
    union { float f; unsigned u; } hf; hf.u = a.u & 0xFFFF0000u;
    union { float f; unsigned u; } lo; lo.f = f[i] - hf.f;
    lu[i] = (u16)(lo.u >> 16);
  }
  h = __builtin_bit_cast(bf16x8, hu);
  l = __builtin_bit_cast(bf16x8, lu);
}
__device__ __forceinline__ bf16x8 cvt8_rne(const float* p) {
  const float4 v0 = *reinterpret_cast<const float4*>(p);
  const float4 v1 = *reinterpret_cast<const float4*>(p + 4);
  const float f[8] = {v0.x, v0.y, v0.z, v0.w, v1.x, v1.y, v1.z, v1.w};
  u16x8 u;
#pragma unroll
  for (int i = 0; i < 8; ++i) u[i] = f2bf_rne(f[i]);
  return __builtin_bit_cast(bf16x8, u);
}
__device__ __forceinline__ f32x4 mfma16(bf16x8 a, bf16x8 b, f32x4 c) {
  return __builtin_amdgcn_mfma_f32_16x16x32_bf16(a, b, c, 0, 0, 0);
}
__device__ __forceinline__ float sigm(float x) {
  return 1.0f / (1.0f + exp2f(-L2E * x));
}
__device__ __forceinline__ float tanh_(float x) {
  return 1.0f - 2.0f / (1.0f + exp2f(2.0f * L2E * x));
}

// ---- hierarchical self-resetting grid barrier ----
// Level 1: 32-block chunks, one 128B-spaced line each (<=32 RMWs + 31 pollers
// per line). Level 2: root line (<=16 RMWs + 15 pollers). Avoids the
// single-line arrive+poll contention collapse of a flat barrier.
__device__ __align__(128) unsigned c_cnt[16 * 32];
__device__ __align__(128) unsigned c_gen[16 * 32];
__device__ __align__(128) unsigned r_cnt = 0;
__device__ __align__(128) unsigned r_gen = 0;
__device__ __align__(128) unsigned gg_cnt[64 * 32];   // per-row-group lines
__device__ __align__(128) unsigned gg_gen[64 * 32];

__device__ __forceinline__ void gbar() {
  __syncthreads();
  if (threadIdx.x == 0) {
    const int ch = blockIdx.x >> 5;
    const unsigned nch = gridDim.x >> 5;
    unsigned* cc = &c_cnt[ch * 32];
    unsigned* cg = &c_gen[ch * 32];
    const unsigned g = __hip_atomic_load(cg, __ATOMIC_RELAXED, __HIP_MEMORY_SCOPE_AGENT);
    const unsigned a = __hip_atomic_fetch_add(cc, 1u, __ATOMIC_ACQ_REL, __HIP_MEMORY_SCOPE_AGENT);
    if (a == 31u) {                       // last arriver of this chunk
      const unsigned rg = __hip_atomic_load(&r_gen, __ATOMIC_RELAXED, __HIP_MEMORY_SCOPE_AGENT);
      const unsigned ra = __hip_atomic_fetch_add(&r_cnt, 1u, __ATOMIC_ACQ_REL, __HIP_MEMORY_SCOPE_AGENT);
      if (ra == nch - 1u) {               // last chunk overall
        __hip_atomic_store(&r_cnt, 0u, __ATOMIC_RELAXED, __HIP_MEMORY_SCOPE_AGENT);
        __hip_atomic_store(&r_gen, rg + 1u, __ATOMIC_RELEASE, __HIP_MEMORY_SCOPE_AGENT);
      } else {
        while (__hip_atomic_load(&r_gen, __ATOMIC_RELAXED, __HIP_MEMORY_SCOPE_AGENT) == rg)
          __builtin_amdgcn_s_sleep(1);
        (void)__hip_atomic_load(&r_gen, __ATOMIC_ACQUIRE, __HIP_MEMORY_SCOPE_AGENT);
      }
      __hip_atomic_store(cc, 0u, __ATOMIC_RELAXED, __HIP_MEMORY_SCOPE_AGENT);
      __hip_atomic_store(cg, g + 1u, __ATOMIC_RELEASE, __HIP_MEMORY_SCOPE_AGENT);
    } else {
      while (__hip_atomic_load(cg, __ATOMIC_RELAXED, __HIP_MEMORY_SCOPE_AGENT) == g)
        __builtin_amdgcn_s_sleep(2);
      (void)__hip_atomic_load(cg, __ATOMIC_ACQUIRE, __HIP_MEMORY_SCOPE_AGENT);
    }
  }
  __syncthreads();
}

__device__ __forceinline__ void gbarg(int grp, unsigned tgt) {
  __syncthreads();
  if (threadIdx.x == 0) {
    unsigned* pc = &gg_cnt[grp * 32];
    unsigned* pg = &gg_gen[grp * 32];
    const unsigned g = __hip_atomic_load(pg, __ATOMIC_RELAXED, __HIP_MEMORY_SCOPE_AGENT);
    const unsigned a = __hip_atomic_fetch_add(pc, 1u, __ATOMIC_ACQ_REL, __HIP_MEMORY_SCOPE_AGENT);
    if (a == tgt - 1u) {
      __hip_atomic_store(pc, 0u, __ATOMIC_RELAXED, __HIP_MEMORY_SCOPE_AGENT);
      __hip_atomic_store(pg, g + 1u, __ATOMIC_RELEASE, __HIP_MEMORY_SCOPE_AGENT);
    } else {
      while (__hip_atomic_load(pg, __ATOMIC_RELAXED, __HIP_MEMORY_SCOPE_AGENT) == g)
        __builtin_amdgcn_s_sleep(2);
      (void)__hip_atomic_load(pg, __ATOMIC_ACQUIRE, __HIP_MEMORY_SCOPE_AGENT);
    }
  }
  __syncthreads();
}

struct MArgs {
  const float *lf, *ah0, *ac0, *aw, *awc, *actx, *dh0, *dc0, *mem, *pm;
  const float *Wih_a, *Whh_a, *bih_a, *bhh_a;
  const float *Wq, *Wv, *Wloc, *Wlfc;
  const float *Wih_d, *Whh_d, *bih_d, *bhh_d;
  const float *Wp, *bp, *Wg, *bg;
  const int *msk;
  float *wsf;
  float *out;
};

__global__ __launch_bounds__(256, 4) void mega(MArgs A)
{
  const int tid  = threadIdx.x;
  const int bid  = blockIdx.x;
  const int gd   = gridDim.x;
  const int gtid = bid * 256 + tid;
  const int gs   = gd * 256;
  const int w    = tid >> 6, lane = tid & 63, quad = lane >> 4, l16 = lane & 15;
  const int G    = gd >> 6;                 // blocks per row group (8 or 4)
  const int lgG  = __popc(G - 1);
  // XCD-local group mapping: members of group b are {b, b+64, ...} and
  // 64 ≡ 0 (mod 8), so under round-robin dispatch they share one XCD.
  const int b    = bid & 63;                // batch row
  const int tch  = bid >> 6;                // slot within group

  // ---- workspace layout (fp32 offsets); everything written before read ----
  float* ga_part = A.wsf;                    // [16][64][4096]  (G planes used)
  float* gd_part = A.wsf + 4194304;          // [16][64][4096]
  float* ctx_p   = A.wsf + 8716288;          // [8][64][256]
  float* ctx     = A.wsf + 8847360;          // [64][256]
  float* ah_f    = A.wsf + 8863744;          // [64][1024]
  float* pq      = A.wsf + 8929280;          // [64][128]
  float* e_g     = A.wsf + 8937472;          // [64][2048]
  u16*  xd       = (u16*)(A.wsf + 9068544);  // [64][1024] bf16 (attn h)
  u16*  dhac     = xd + 65536;               // [64][1280] bf16
  u16*  w2b      = dhac + 81920;             // [128][64] bf16
  float* out     = A.out;
  float* out_w   = A.out + 16448;

  __shared__ __align__(16) u16 awin[2][64];
  __shared__ __align__(16) u16 pms[32 * 128];
  __shared__ __align__(16) u16 w2s[128 * 64];
  __shared__ float wvs[128];
  __shared__ float pqs[128];
  __shared__ float es[32];
  __shared__ float red4[4];
  __shared__ float wsm[256];
  __shared__ float redc[4][256];             // also reused as epi_a pre-gates

  // ============== P1: attn-LSTM GEMM partials + w2b fold ==============
  {
    const int jt = b, ksp = tch;              // 64 j-tiles x G k-planes
    const int g = w;
    const int n = g * 1024 + jt * 16 + l16;
    const int s0 = (ksp * 44) >> lgG, s1 = ((ksp + 1) * 44) >> lgG;
    f32x4 acc[4] = {{0,0,0,0},{0,0,0,0},{0,0,0,0},{0,0,0,0}};
    for (int s = s0; s < s1; ++s) {
      const int k = s * 32 + quad * 8;
      const float* bp = (k < 384) ? (A.Wih_a + n * 384 + k) : (A.Whh_a + n * 1024 + (k - 384));
      bf16x8 b_h, b_l; split8t(bp, b_h, b_l);
#pragma unroll
      for (int mt = 0; mt < 4; ++mt) {
        const int mA = mt * 16 + l16;
        const float* ap;
        if (k < 128)      ap = A.lf   + mA * 128  + k;
        else if (k < 384) ap = A.actx + mA * 256  + (k - 128);
        else              ap = A.ah0  + mA * 1024 + (k - 384);
        bf16x8 a_h, a_l; split8t(ap, a_h, a_l);
        acc[mt] = mfma16(a_h, b_h, acc[mt]);
        acc[mt] = mfma16(a_h, b_l, acc[mt]);
        acc[mt] = mfma16(a_l, b_h, acc[mt]);
      }
    }
    float* dst = ga_part + (size_t)ksp * 262144;
#pragma unroll
    for (int mt = 0; mt < 4; ++mt)
#pragma unroll
      for (int r = 0; r < 4; ++r)
        dst[(mt * 16 + quad * 4 + r) * 4096 + n] = acc[mt][r];
    // fold W2[a][k] = sum_f Wlfc[a,f] * Wloc[f,c,dk] (tiny, grid-strided)
    for (int lin = gtid; lin < 8192; lin += gs) {
      const int a = lin >> 6, k2 = lin & 63;
      float v = 0.0f;
      if (k2 < 62) {
        const int c = (k2 >= 31) ? 1 : 0, dk = k2 - c * 31;
        for (int f = 0; f < 32; ++f)
          v += A.Wlfc[a * 32 + f] * A.Wloc[f * 62 + c * 31 + dk];
      }
      w2b[a * 64 + k2] = f2bf_rne(v);
    }
  }
  gbar();                                    // GB1

  // stage w2s once (read in energy phase)
  {
    const int i0 = tid * 32;
#pragma unroll
    for (int q = 0; q < 4; ++q)
      *reinterpret_cast<u16x8*>(&w2s[i0 + q * 8]) = *reinterpret_cast<const u16x8*>(&w2b[i0 + q * 8]);
  }

  // ---- A1: epi_a for row b (slice of 1024/G gate columns) ----
  {
    const int cnt = 1024 >> lgG;
    const int lgc = 10 - lgG;
    const int j0 = tch * cnt;
    for (int idx = tid; idx < cnt * 4; idx += 256) {
      const int g = idx >> lgc, jj = idx & (cnt - 1);
      const int col = g * 1024 + j0 + jj;
      float s = 0.0f;
      for (int ks = 0; ks < G; ++ks)
        s += ga_part[(size_t)ks * 262144 + b * 4096 + col];
      redc[g][jj] = s;
    }
    __syncthreads();
    for (int jj = tid; jj < cnt; jj += 256) {
      const int j = j0 + jj;
      const float pi = redc[0][jj] + A.bih_a[j]        + A.bhh_a[j];
      const float pf = redc[1][jj] + A.bih_a[1024 + j] + A.bhh_a[1024 + j];
      const float pg = redc[2][jj] + A.bih_a[2048 + j] + A.bhh_a[2048 + j];
      const float po = redc[3][jj] + A.bih_a[3072 + j] + A.bhh_a[3072 + j];
      const float c2 = sigm(pf) * A.ac0[b * 1024 + j] + sigm(pi) * tanh_(pg);
      const float h2 = sigm(po) * tanh_(c2);
      ah_f[b * 1024 + j] = h2;
      xd[b * 1024 + j]   = f2bf_rne(h2);
    }
  }
  gbarg(b, G);                               // ah[b] complete

  // ---- A2: pq[b][a-slice] = ah[b] . Wq[a] ----
  {
    const int cntA = 128 >> lgG;
    const int perW = cntA >> 2;
    const int a0 = tch * cntA + w * perW;
    for (int i = 0; i < perW; ++i) {
      const int a = a0 + i;
      float s = 0.0f;
      for (int k = lane; k < 1024; k += 64)
        s += A.Wq[a * 1024 + k] * ah_f[b * 1024 + k];
      for (int off = 1; off < 64; off <<= 1) s += __shfl_xor(s, off, 64);
      if (lane == 0) pq[b * 128 + a] = s;
    }
  }
  gbarg(b, G);                               // pq[b] complete

  // ---- A3: energies, tiles of 32 t strided by G ----
  if (tid < 128) { wvs[tid] = A.Wv[tid]; pqs[tid] = pq[b * 128 + tid]; }
  {
    const int mt_ = w & 1, ng = w >> 1;
    for (int tile = tch; tile < 64; tile += G) {
      const int t0 = tile * 32;
      __syncthreads();                       // guard LDS overwrite vs prev readers
      if (tid < 128) {
        const int c = tid >> 6, ii = tid & 63;
        const int t = t0 - 15 + ii;
        float v = 0.0f;
        if (ii < 62 && t >= 0 && t < 2048) v = (c ? A.awc : A.aw)[b * 2048 + t];
        awin[c][ii] = f2bf_rne(v);
      }
      if (tid < 32) es[tid] = 0.0f;
      {
        const float* src = A.pm + (size_t)b * 262144 + (size_t)t0 * 128;
        const int i = tid * 16;
#pragma unroll
        for (int q = 0; q < 4; ++q) {
          const float4 v = *reinterpret_cast<const float4*>(&src[i + q * 4]);
          pms[i + q * 4 + 0] = f2bf_rne(v.x);
          pms[i + q * 4 + 1] = f2bf_rne(v.y);
          pms[i + q * 4 + 2] = f2bf_rne(v.z);
          pms[i + q * 4 + 3] = f2bf_rne(v.w);
        }
      }
      __syncthreads();
      f32x4 acc[4] = {{0,0,0,0},{0,0,0,0},{0,0,0,0},{0,0,0,0}};
#pragma unroll
      for (int ksx = 0; ksx < 2; ++ksx) {
        bf16x8 af;
        const int m2 = mt_ * 16 + l16;
#pragma unroll
        for (int jj = 0; jj < 8; ++jj) {
          const int k = ksx * 32 + quad * 8 + jj;
          u16 v = 0;
          if (k < 62) { const int c = (k >= 31) ? 1 : 0; const int dk = k - c * 31; v = awin[c][m2 + dk]; }
          af[jj] = __builtin_bit_cast(__bf16, v);
        }
#pragma unroll
        for (int p = 0; p < 4; ++p) {
          const int a = (ng * 4 + p) * 16 + l16;
          bf16x8 bfr = *reinterpret_cast<const bf16x8*>(&w2s[a * 64 + ksx * 32 + quad * 8]);
          acc[p] = mfma16(af, bfr, acc[p]);
        }
      }
#pragma unroll
      for (int r = 0; r < 4; ++r) {
        const int tl = mt_ * 16 + quad * 4 + r;
        float part = 0.0f;
#pragma unroll
        for (int p = 0; p < 4; ++p) {
          const int a = (ng * 4 + p) * 16 + l16;
          const float x = pqs[a] + bf2f(pms[tl * 128 + a]) + acc[p][r];
          part += wvs[a] * tanh_(x);
        }
        part += __shfl_xor(part, 1, 64);
        part += __shfl_xor(part, 2, 64);
        part += __shfl_xor(part, 4, 64);
        part += __shfl_xor(part, 8, 64);
        if (l16 == 0) atomicAdd(&es[tl], part);
      }
      __syncthreads();
      if (tid < 32) {
        const int t = t0 + tid;
        e_g[b * 2048 + t] = A.msk[b * 2048 + t] ? -1e30f : es[tid];
      }
    }
  }
  gbarg(b, G);                               // e_g[b] complete

  // ---- A4: softmax (full-row stats) + ctx partials + out_w ----
  for (int tc = tch; tc < 8; tc += G) {
    __syncthreads();                         // guard red4/wsm/redc reuse
    float v8[8];
    float mx = -3.0e38f;
#pragma unroll
    for (int i = 0; i < 8; ++i) { v8[i] = e_g[b * 2048 + tid + i * 256]; mx = fmaxf(mx, v8[i]); }
    for (int off = 1; off < 64; off <<= 1) mx = fmaxf(mx, __shfl_xor(mx, off, 64));
    if ((tid & 63) == 0) red4[tid >> 6] = mx;
    __syncthreads();
    mx = fmaxf(fmaxf(red4[0], red4[1]), fmaxf(red4[2], red4[3]));
    float ex[8], s = 0.0f;
#pragma unroll
    for (int i = 0; i < 8; ++i) { ex[i] = exp2f((v8[i] - mx) * L2E); s += ex[i]; }
    for (int off = 1; off < 64; off <<= 1) s += __shfl_xor(s, off, 64);
    __syncthreads();
    if ((tid & 63) == 0) red4[tid >> 6] = s;
    __syncthreads();
    const float rs = 1.0f / (red4[0] + red4[1] + red4[2] + red4[3]);
    float exc = 0.0f;                        // static-index select
#pragma unroll
    for (int i = 0; i < 8; ++i) if (i == tc) exc = ex[i];
    const float wv = exc * rs;
    out_w[b * 2048 + tc * 256 + tid] = wv;
    wsm[tid] = wv;
    __syncthreads();
    const float* mp = A.mem + (size_t)b * 524288 + ((size_t)tc * 256 + w * 64) * 256 + lane * 4;
    f32x4 acc = {0, 0, 0, 0};
#pragma unroll 8
    for (int t = 0; t < 64; ++t) {
      const float wt = wsm[w * 64 + t];
      const float4 v = *reinterpret_cast<const float4*>(mp + (size_t)t * 256);
      acc[0] += wt * v.x; acc[1] += wt * v.y; acc[2] += wt * v.z; acc[3] += wt * v.w;
    }
#pragma unroll
    for (int i = 0; i < 4; ++i) redc[w][lane * 4 + i] = acc[i];
    __syncthreads();
    const float s2 = redc[0][tid] + redc[1][tid] + redc[2][tid] + redc[3][tid];
    ctx_p[tc * 16384 + b * 256 + tid] = s2;
  }
  gbarg(b, G);                               // ctx partials complete

  // ---- A5: ctx sum + bf16 slice of dhac (one block per group) ----
  if (tch == 0) {
    float s = 0.0f;
#pragma unroll
    for (int tc = 0; tc < 8; ++tc) s += ctx_p[tc * 16384 + b * 256 + tid];
    ctx[b * 256 + tid] = s;
    dhac[b * 1280 + 1024 + tid] = f2bf_rne(s);
  }
  gbar();                                    // GB2: xd, ctx, dhac-ctx ready

  // ============== P8: dec-LSTM GEMM partials (split-K = G) ==============
  {
    const int jt = b, ksp = tch;
    const int g = w;
    const int n = g * 1024 + jt * 16 + l16;
    const int s0 = (ksp * 72) >> lgG, s1 = ((ksp + 1) * 72) >> lgG;
    f32x4 acc[4] = {{0,0,0,0},{0,0,0,0},{0,0,0,0},{0,0,0,0}};
    for (int s = s0; s < s1; ++s) {
      const int k = s * 32 + quad * 8;
      const float* bp = (k < 1280) ? (A.Wih_d + n * 1280 + k) : (A.Whh_d + n * 1024 + (k - 1280));
      bf16x8 b_h, b_l; split8t(bp, b_h, b_l);
      if (k < 1024) {
#pragma unroll
        for (int mt = 0; mt < 4; ++mt) {
          bf16x8 a_h = ldb(xd + (mt * 16 + l16) * 1024 + k);
          acc[mt] = mfma16(a_h, b_h, acc[mt]);
          acc[mt] = mfma16(a_h, b_l, acc[mt]);
        }
      } else if (k < 1280) {
#pragma unroll
        for (int mt = 0; mt < 4; ++mt) {
          bf16x8 a_h = cvt8_rne(ctx + (mt * 16 + l16) * 256 + (k - 1024));
          acc[mt] = mfma16(a_h, b_h, acc[mt]);
          acc[mt] = mfma16(a_h, b_l, acc[mt]);
        }
      } else {
#pragma unroll
        for (int mt = 0; mt < 4; ++mt) {
          bf16x8 a_h, a_l; split8t(A.dh0 + (mt * 16 + l16) * 1024 + (k - 1280), a_h, a_l);
          acc[mt] = mfma16(a_h, b_h, acc[mt]);
          acc[mt] = mfma16(a_h, b_l, acc[mt]);
          acc[mt] = mfma16(a_l, b_h, acc[mt]);
        }
      }
    }
    float* dst = gd_part + (size_t)ksp * 262144;
#pragma unroll
    for (int mt = 0; mt < 4; ++mt)
#pragma unroll
      for (int r = 0; r < 4; ++r)
        dst[(mt * 16 + quad * 4 + r) * 4096 + n] = acc[mt][r];
  }
  gbar();                                    // GB3

  // ---- B1: dec epilogue for row b (col slice) ----
  {
    const int cnt = 1024 >> lgG;
    const int j0 = tch * cnt;
    for (int jj = tid; jj < cnt; jj += 256) {
      const int j = j0 + jj;
      float p4[4] = {0, 0, 0, 0};
      for (int ks = 0; ks < G; ++ks) {
        const float* gp = gd_part + (size_t)ks * 262144 + b * 4096 + j;
        p4[0] += gp[0];
        p4[1] += gp[1024];
        p4[2] += gp[2048];
        p4[3] += gp[3072];
      }
      const float pi = p4[0] + A.bih_d[j]        + A.bhh_d[j];
      const float pf = p4[1] + A.bih_d[1024 + j] + A.bhh_d[1024 + j];
      const float pg = p4[2] + A.bih_d[2048 + j] + A.bhh_d[2048 + j];
      const float po = p4[3] + A.bih_d[3072 + j] + A.bhh_d[3072 + j];
      const float c2 = sigm(pf) * A.dc0[b * 1024 + j] + sigm(pi) * tanh_(pg);
      const float h2 = sigm(po) * tanh_(c2);
      dhac[b * 1280 + j] = f2bf_rne(h2);
    }
  }
  gbarg(b, G);                               // dhac[b] complete

  // ---- B2: proj row b (col slice) + stop gate; no more barriers ----
  {
    const int cpb = 256 >> lgG;              // cols per block
    const int n0 = tch * cpb;
    for (int c = w; c < cpb; c += 4) {
      const int n = n0 + c;
      float s = 0.0f;
      for (int k = lane; k < 1280; k += 64)
        s += bf2f(dhac[b * 1280 + k]) * A.Wp[n * 1280 + k];
      for (int off = 1; off < 64; off <<= 1) s += __shfl_xor(s, off, 64);
      if (lane == 0) out[b * 256 + n] = s + A.bp[n];
    }
    if (tch == 0 && w == 0) {
      float s = 0.0f;
      for (int k = lane; k < 1280; k += 64)
        s += bf2f(dhac[b * 1280 + k]) * A.Wg[k];
      for (int off = 1; off < 64; off <<= 1) s += __shfl_xor(s, off, 64);
      if (lane == 0) out[16384 + b] = s + A.bg[0];
    }
  }
}

extern "C" void kernel_launch(void* const* d_in, const int* in_sizes, int n_in,
                              void* d_out, int out_size, void* d_ws, size_t ws_size,
                              hipStream_t stream)
{
  (void)in_sizes; (void)n_in; (void)out_size; (void)ws_size;
  MArgs a;
  a.lf    = (const float*)d_in[0];
  a.ah0   = (const float*)d_in[1];
  a.ac0   = (const float*)d_in[2];
  a.aw    = (const float*)d_in[3];
  a.awc   = (const float*)d_in[4];
  a.actx  = (const float*)d_in[5];
  a.dh0   = (const float*)d_in[6];
  a.dc0   = (const float*)d_in[7];
  a.mem   = (const float*)d_in[8];
  a.pm    = (const float*)d_in[9];
  a.Wih_a = (const float*)d_in[10];
  a.Whh_a = (const float*)d_in[11];
  a.bih_a = (const float*)d_in[12];
  a.bhh_a = (const float*)d_in[13];
  a.Wq    = (const float*)d_in[14];
  a.Wv    = (const float*)d_in[15];
  a.Wloc  = (const float*)d_in[16];
  a.Wlfc  = (const float*)d_in[17];
  a.Wih_d = (const float*)d_in[18];
  a.Whh_d = (const float*)d_in[19];
  a.bih_d = (const float*)d_in[20];
  a.bhh_d = (const float*)d_in[21];
  a.Wp    = (const float*)d_in[22];
  a.bp    = (const float*)d_in[23];
  a.Wg    = (const float*)d_in[24];
  a.bg    = (const float*)d_in[25];
  a.msk   = (const int*)d_in[26];
  a.wsf   = (float*)d_ws;
  a.out   = (float*)d_out;

  // Plain launch; grid clamped to guaranteed-resident capacity so the
  // self-built barriers cannot deadlock. 512 blocks (2/CU) preferred:
  // phases are not TLP-starved and barrier cost scales with arrivals.
  static int nblk = 0;
  if (nblk == 0) {
    int occ = 0, dev = 0, ncu = 0;
    (void)hipGetDevice(&dev);
    (void)hipDeviceGetAttribute(&ncu, hipDeviceAttributeMultiprocessorCount, dev);
    (void)hipOccupancyMaxActiveBlocksPerMultiprocessor(&occ, mega, 256, 0);
    if (ncu <= 0) ncu = 256;
    if (occ <= 0) occ = 2;
    const int cap = occ * ncu;
    nblk = (cap >= 512) ? 512 : 256;        // G = 8 / 4
  }

  mega<<<dim3(nblk), dim3(256), 0, stream>>>(a);
}

// Round 4
// 389.149 us; speedup vs baseline: 1.5337x; 1.5337x over previous
//
#include <hip/hip_runtime.h>
#include <stdint.h>

typedef unsigned short u16;
typedef __attribute__((ext_vector_type(8))) u16 u16x8;
typedef __attribute__((ext_vector_type(8))) __bf16 bf16x8;
typedef __attribute__((ext_vector_type(4))) float f32x4;

#define L2E 1.4426950408889634f

__device__ __forceinline__ float bf2f(u16 u) {
  union { unsigned i; float f; } v; v.i = ((unsigned)u) << 16; return v.f;
}
__device__ __forceinline__ u16 f2bf_rne(float f) {
  union { float f; unsigned u; } v; v.f = f;
  const unsigned r = v.u + 0x7FFFu + ((v.u >> 16) & 1u);
  return (u16)(r >> 16);
}
__device__ __forceinline__ bf16x8 ldb(const u16* p) {
  u16x8 v = *reinterpret_cast<const u16x8*>(p);
  return __builtin_bit_cast(bf16x8, v);
}
// fp32 -> split bf16 via truncation: f = hi + lo + O(2^-16 |f|)
__device__ __forceinline__ void split8t(const float* p, bf16x8& h, bf16x8& l) {
  const float4 v0 = *reinterpret_cast<const float4*>(p);
  const float4 v1 = *reinterpret_cast<const float4*>(p + 4);
  const float f[8] = {v0.x, v0.y, v0.z, v0.w, v1.x, v1.y, v1.z, v1.w};
  u16x8 hu, lu;
#pragma unroll
  for (int i = 0; i < 8; ++i) {
    union { float f; unsigned u; } a; a.f = f[i];
    hu[i] = (u16)(a.u >> 16);
    union { float f; unsigned u; } hf; hf.u = a.u & 0xFFFF0000u;
    union { float f; unsigned u; } lo; lo.f = f[i] - hf.f;
    lu[i] = (u16)(lo.u >> 16);
  }
  h = __builtin_bit_cast(bf16x8, hu);
  l = __builtin_bit_cast(bf16x8, lu);
}
__device__ __forceinline__ bf16x8 cvt8_rne(const float* p) {
  const float4 v0 = *reinterpret_cast<const float4*>(p);
  const float4 v1 = *reinterpret_cast<const float4*>(p + 4);
  const float f[8] = {v0.x, v0.y, v0.z, v0.w, v1.x, v1.y, v1.z, v1.w};
  u16x8 u;
#pragma unroll
  for (int i = 0; i < 8; ++i) u[i] = f2bf_rne(f[i]);
  return __builtin_bit_cast(bf16x8, u);
}
__device__ __forceinline__ f32x4 mfma16(bf16x8 a, bf16x8 b, f32x4 c) {
  return __builtin_amdgcn_mfma_f32_16x16x32_bf16(a, b, c, 0, 0, 0);
}
__device__ __forceinline__ float sigm(float x) {
  return 1.0f / (1.0f + exp2f(-L2E * x));
}
__device__ __forceinline__ float tanh_(float x) {
  return 1.0f - 2.0f / (1.0f + exp2f(2.0f * L2E * x));
}

// ---------------------------------------------------------------------------
// K0: fold W2[a][k] = sum_f W_lfc[a,f] * W_loc[f,c,dk]  (k = c*31+dk, pad 64)
// ---------------------------------------------------------------------------
__global__ __launch_bounds__(128) void k0_prep(
    const float* __restrict__ Wloc, const float* __restrict__ Wlfc,
    u16* __restrict__ w2b)
{
  const int k = blockIdx.x, a = threadIdx.x;   // grid 64, block 128
  float v = 0.0f;
  if (k < 62) {
    const int c = (k >= 31) ? 1 : 0, dk = k - c * 31;
    for (int f = 0; f < 32; ++f)
      v += Wlfc[a * 32 + f] * Wloc[f * 62 + c * 31 + dk];
  }
  w2b[a * 64 + k] = f2bf_rne(v);
}

// ---------------------------------------------------------------------------
// K1 GEMM: split-K partial planes of gates_a = [lf|actx|ah0] @ [Wih|Whh]^T.
// grid (64 j-tiles, 8 k-chunks); no atomics, deterministic plane writes.
// ---------------------------------------------------------------------------
__global__ __launch_bounds__(256) void k1_gemm(
    const float* __restrict__ lf, const float* __restrict__ actx,
    const float* __restrict__ ah_in,
    const float* __restrict__ Wih, const float* __restrict__ Whh,
    float* __restrict__ gpart)
{
  const int tid = threadIdx.x;
  const int g = tid >> 6, lane = tid & 63, quad = lane >> 4, l16 = lane & 15;
  const int jb = blockIdx.x * 16, ks = blockIdx.y;
  const int n = g * 1024 + jb + l16;
  const int s0 = (ks * 44) / 8, s1 = ((ks + 1) * 44) / 8;
  f32x4 acc[4] = {{0,0,0,0},{0,0,0,0},{0,0,0,0},{0,0,0,0}};
  for (int s = s0; s < s1; ++s) {
    const int k = s * 32 + quad * 8;
    const float* bp = (k < 384) ? (Wih + n * 384 + k) : (Whh + n * 1024 + (k - 384));
    bf16x8 b_h, b_l; split8t(bp, b_h, b_l);
#pragma unroll
    for (int mt = 0; mt < 4; ++mt) {
      const int mA = mt * 16 + l16;
      const float* ap;
      if (k < 128)      ap = lf    + mA * 128  + k;
      else if (k < 384) ap = actx  + mA * 256  + (k - 128);
      else              ap = ah_in + mA * 1024 + (k - 384);
      bf16x8 a_h, a_l; split8t(ap, a_h, a_l);
      acc[mt] = mfma16(a_h, b_h, acc[mt]);
      acc[mt] = mfma16(a_h, b_l, acc[mt]);
      acc[mt] = mfma16(a_l, b_h, acc[mt]);
    }
  }
  float* dst = gpart + (size_t)ks * 262144;
#pragma unroll
  for (int mt = 0; mt < 4; ++mt)
#pragma unroll
    for (int r = 0; r < 4; ++r)
      dst[(mt * 16 + quad * 4 + r) * 4096 + n] = acc[mt][r];
}

// ---------------------------------------------------------------------------
// K1 epilogue: sum 8 planes + LSTM -> ah_f fp32 + xd bf16
// ---------------------------------------------------------------------------
__global__ __launch_bounds__(256) void k1_epi(
    const float* __restrict__ gpart, const float* __restrict__ ac_in,
    const float* __restrict__ bih, const float* __restrict__ bhh,
    float* __restrict__ ah_f, u16* __restrict__ xd)
{
  const int lin = blockIdx.x * 256 + threadIdx.x;   // 64*1024
  const int m = lin >> 10, j = lin & 1023;
  float p4[4] = {0, 0, 0, 0};
  for (int ks = 0; ks < 8; ++ks) {
    const float* gp = gpart + (size_t)ks * 262144 + m * 4096 + j;
    p4[0] += gp[0];
    p4[1] += gp[1024];
    p4[2] += gp[2048];
    p4[3] += gp[3072];
  }
  const float pi = p4[0] + bih[j]        + bhh[j];
  const float pf = p4[1] + bih[1024 + j] + bhh[1024 + j];
  const float pg = p4[2] + bih[2048 + j] + bhh[2048 + j];
  const float po = p4[3] + bih[3072 + j] + bhh[3072 + j];
  const float c2 = sigm(pf) * ac_in[m * 1024 + j] + sigm(pi) * tanh_(pg);
  const float h2 = sigm(po) * tanh_(c2);
  ah_f[m * 1024 + j] = h2;
  xd[m * 1024 + j]   = f2bf_rne(h2);
}

// ---------------------------------------------------------------------------
// K2a: pq[b][a] = ah[b] . W_q[a], coalesced float4 along K.
// grid (8 a-chunks, 64 b); wave w handles 4 consecutive a.
// ---------------------------------------------------------------------------
__global__ __launch_bounds__(256) void k2a_pq(
    const float* __restrict__ ah_f, const float* __restrict__ Wq,
    float* __restrict__ pq)
{
  const int b = blockIdx.y, ch = blockIdx.x;
  const int w = threadIdx.x >> 6, lane = threadIdx.x & 63;
  const float4* xp = reinterpret_cast<const float4*>(ah_f + b * 1024);
  float4 x[4];
#pragma unroll
  for (int it = 0; it < 4; ++it) x[it] = xp[it * 64 + lane];
#pragma unroll
  for (int i = 0; i < 4; ++i) {
    const int a = ch * 16 + w * 4 + i;
    const float4* wp = reinterpret_cast<const float4*>(Wq + a * 1024);
    float s = 0.0f;
#pragma unroll
    for (int it = 0; it < 4; ++it) {
      const float4 q = wp[it * 64 + lane];
      s += q.x * x[it].x + q.y * x[it].y + q.z * x[it].z + q.w * x[it].w;
    }
    for (int off = 1; off < 64; off <<= 1) s += __shfl_xor(s, off, 64);
    if (lane == 0) pq[b * 128 + a] = s;
  }
}

// ---------------------------------------------------------------------------
// K2: per (b, 32-t tile): folded location conv as bf16 MFMA, then
// e[b,t] = sum_a Wv[a]*tanh(pq + pm + loc), masked -> fp32.
// ---------------------------------------------------------------------------
__global__ __launch_bounds__(256) void k2_energy(
    const float* __restrict__ aw, const float* __restrict__ awc,
    const float* __restrict__ pm, const float* __restrict__ Wv,
    const float* __restrict__ pq, const u16* __restrict__ w2b,
    const int* __restrict__ msk, float* __restrict__ e_g)
{
  __shared__ __align__(16) u16 awin[2][64];
  __shared__ __align__(16) u16 pms[32 * 128];
  __shared__ __align__(16) u16 w2s[128 * 64];
  __shared__ float wvs[128];
  __shared__ float pqs[128];
  __shared__ float es[32];
  const int b = blockIdx.y, t0 = blockIdx.x * 32, tid = threadIdx.x;

  if (tid < 128) {
    const int c = tid >> 6, ii = tid & 63;
    const int t = t0 - 15 + ii;
    float v = 0.0f;
    if (ii < 62 && t >= 0 && t < 2048) v = (c ? awc : aw)[b * 2048 + t];
    awin[c][ii] = f2bf_rne(v);
    wvs[tid] = Wv[tid];
    pqs[tid] = pq[b * 128 + tid];
  }
  if (tid < 32) es[tid] = 0.0f;
  {
    const float* src = pm + (size_t)b * 262144 + (size_t)t0 * 128;
    const int i = tid * 16;
#pragma unroll
    for (int q = 0; q < 4; ++q) {
      const float4 v = *reinterpret_cast<const float4*>(&src[i + q * 4]);
      pms[i + q * 4 + 0] = f2bf_rne(v.x);
      pms[i + q * 4 + 1] = f2bf_rne(v.y);
      pms[i + q * 4 + 2] = f2bf_rne(v.z);
      pms[i + q * 4 + 3] = f2bf_rne(v.w);
    }
  }
  {
    const int i = tid * 32;
#pragma unroll
    for (int q = 0; q < 4; ++q)
      *reinterpret_cast<u16x8*>(&w2s[i + q * 8]) = *reinterpret_cast<const u16x8*>(&w2b[i + q * 8]);
  }
  __syncthreads();

  const int w = tid >> 6, lane = tid & 63, quad = lane >> 4, l16 = lane & 15;
  const int mt = w & 1, ng = w >> 1;
  f32x4 acc[4] = {{0,0,0,0},{0,0,0,0},{0,0,0,0},{0,0,0,0}};
#pragma unroll
  for (int ksx = 0; ksx < 2; ++ksx) {
    bf16x8 af;
    const int m = mt * 16 + l16;
#pragma unroll
    for (int jj = 0; jj < 8; ++jj) {
      const int k = ksx * 32 + quad * 8 + jj;
      u16 v = 0;
      if (k < 62) { const int c = (k >= 31) ? 1 : 0; const int dk = k - c * 31; v = awin[c][m + dk]; }
      af[jj] = __builtin_bit_cast(__bf16, v);
    }
#pragma unroll
    for (int p = 0; p < 4; ++p) {
      const int a = (ng * 4 + p) * 16 + l16;
      bf16x8 bfr = *reinterpret_cast<const bf16x8*>(&w2s[a * 64 + ksx * 32 + quad * 8]);
      acc[p] = mfma16(af, bfr, acc[p]);
    }
  }
#pragma unroll
  for (int r = 0; r < 4; ++r) {
    const int tl = mt * 16 + quad * 4 + r;
    float part = 0.0f;
#pragma unroll
    for (int p = 0; p < 4; ++p) {
      const int a = (ng * 4 + p) * 16 + l16;
      const float x = pqs[a] + bf2f(pms[tl * 128 + a]) + acc[p][r];
      part += wvs[a] * tanh_(x);
    }
    part += __shfl_xor(part, 1, 64);
    part += __shfl_xor(part, 2, 64);
    part += __shfl_xor(part, 4, 64);
    part += __shfl_xor(part, 8, 64);
    if (l16 == 0) atomicAdd(&es[tl], part);
  }
  __syncthreads();
  if (tid < 32) {
    const int t = t0 + tid;
    e_g[b * 2048 + t] = msk[b * 2048 + t] ? -1e30f : es[tid];
  }
}

// ---------------------------------------------------------------------------
// K3f: fused softmax + ctx partial + out_w. grid (8 t-chunks, 64 b).
// Each block recomputes full-row stats from e_g (8KB, bit-identical), then
// weights its 256-t chunk of mem into a ctx partial plane.
// ---------------------------------------------------------------------------
__global__ __launch_bounds__(256) void k3f_ctx(
    const float* __restrict__ e_g, const float* __restrict__ mem,
    float* __restrict__ ctx_p, float* __restrict__ out_w)
{
  const int tc = blockIdx.x, b = blockIdx.y, tid = threadIdx.x;
  const int w = tid >> 6, lane = tid & 63;
  __shared__ float red4[4];
  __shared__ float wsm[256];
  __shared__ float redc[4][256];
  float v8[8];
  float mx = -3.0e38f;
#pragma unroll
  for (int i = 0; i < 8; ++i) { v8[i] = e_g[b * 2048 + tid + i * 256]; mx = fmaxf(mx, v8[i]); }
  for (int off = 1; off < 64; off <<= 1) mx = fmaxf(mx, __shfl_xor(mx, off, 64));
  if ((tid & 63) == 0) red4[tid >> 6] = mx;
  __syncthreads();
  mx = fmaxf(fmaxf(red4[0], red4[1]), fmaxf(red4[2], red4[3]));
  float ex[8], s = 0.0f;
#pragma unroll
  for (int i = 0; i < 8; ++i) { ex[i] = exp2f((v8[i] - mx) * L2E); s += ex[i]; }
  for (int off = 1; off < 64; off <<= 1) s += __shfl_xor(s, off, 64);
  __syncthreads();
  if ((tid & 63) == 0) red4[tid >> 6] = s;
  __syncthreads();
  const float rs = 1.0f / (red4[0] + red4[1] + red4[2] + red4[3]);
  float exc = 0.0f;                      // static-index select (avoid scratch)
#pragma unroll
  for (int i = 0; i < 8; ++i) if (i == tc) exc = ex[i];
  const float wv = exc * rs;
  out_w[b * 2048 + tc * 256 + tid] = wv;
  wsm[tid] = wv;
  __syncthreads();
  const float* mp = mem + (size_t)b * 524288 + ((size_t)tc * 256 + w * 64) * 256 + lane * 4;
  f32x4 acc = {0, 0, 0, 0};
#pragma unroll 8
  for (int t = 0; t < 64; ++t) {
    const float wt = wsm[w * 64 + t];
    const float4 v = *reinterpret_cast<const float4*>(mp + (size_t)t * 256);
    acc[0] += wt * v.x; acc[1] += wt * v.y; acc[2] += wt * v.z; acc[3] += wt * v.w;
  }
#pragma unroll
  for (int i = 0; i < 4; ++i) redc[w][lane * 4 + i] = acc[i];
  __syncthreads();
  const float s2 = redc[0][tid] + redc[1][tid] + redc[2][tid] + redc[3][tid];
  ctx_p[tc * 16384 + b * 256 + tid] = s2;
}

// ---------------------------------------------------------------------------
// K3s: ctx plane sum -> ctx fp32 + dhac ctx half (bf16). grid 64 x 256.
// ---------------------------------------------------------------------------
__global__ __launch_bounds__(256) void k3s_sum(
    const float* __restrict__ ctx_p, float* __restrict__ ctx,
    u16* __restrict__ dhac)
{
  const int b = blockIdx.x, e = threadIdx.x;
  float s = 0.0f;
#pragma unroll
  for (int tc = 0; tc < 8; ++tc) s += ctx_p[tc * 16384 + b * 256 + e];
  ctx[b * 256 + e] = s;
  dhac[b * 1280 + 1024 + e] = f2bf_rne(s);
}

// ---------------------------------------------------------------------------
// K4 GEMM: split-K partial planes of gates_d = [xd|ctx|dh0] @ [Wih|Whh]^T.
// grid (64 j-tiles, 8 k-chunks of 9x32).
// ---------------------------------------------------------------------------
__global__ __launch_bounds__(256) void k4_gemm(
    const u16* __restrict__ xd, const float* __restrict__ ctx,
    const float* __restrict__ dh_in,
    const float* __restrict__ Wih, const float* __restrict__ Whh,
    float* __restrict__ gpart)
{
  const int tid = threadIdx.x;
  const int g = tid >> 6, lane = tid & 63, quad = lane >> 4, l16 = lane & 15;
  const int jb = blockIdx.x * 16, ks = blockIdx.y;
  const int n = g * 1024 + jb + l16;
  f32x4 acc[4] = {{0,0,0,0},{0,0,0,0},{0,0,0,0},{0,0,0,0}};
  for (int s = ks * 9; s < ks * 9 + 9; ++s) {
    const int k = s * 32 + quad * 8;
    const float* bp = (k < 1280) ? (Wih + n * 1280 + k) : (Whh + n * 1024 + (k - 1280));
    bf16x8 b_h, b_l; split8t(bp, b_h, b_l);
    if (k < 1024) {
#pragma unroll
      for (int mt = 0; mt < 4; ++mt) {
        bf16x8 a_h = ldb(xd + (mt * 16 + l16) * 1024 + k);
        acc[mt] = mfma16(a_h, b_h, acc[mt]);
        acc[mt] = mfma16(a_h, b_l, acc[mt]);
      }
    } else if (k < 1280) {
#pragma unroll
      for (int mt = 0; mt < 4; ++mt) {
        bf16x8 a_h = cvt8_rne(ctx + (mt * 16 + l16) * 256 + (k - 1024));
        acc[mt] = mfma16(a_h, b_h, acc[mt]);
        acc[mt] = mfma16(a_h, b_l, acc[mt]);
      }
    } else {
#pragma unroll
      for (int mt = 0; mt < 4; ++mt) {
        bf16x8 a_h, a_l; split8t(dh_in + (mt * 16 + l16) * 1024 + (k - 1280), a_h, a_l);
        acc[mt] = mfma16(a_h, b_h, acc[mt]);
        acc[mt] = mfma16(a_h, b_l, acc[mt]);
        acc[mt] = mfma16(a_l, b_h, acc[mt]);
      }
    }
  }
  float* dst = gpart + (size_t)ks * 262144;
#pragma unroll
  for (int mt = 0; mt < 4; ++mt)
#pragma unroll
    for (int r = 0; r < 4; ++r)
      dst[(mt * 16 + quad * 4 + r) * 4096 + n] = acc[mt][r];
}

// ---------------------------------------------------------------------------
// K4 epilogue: sum 8 planes + LSTM -> dhac bf16 (cols 0..1023)
// ---------------------------------------------------------------------------
__global__ __launch_bounds__(256) void k4_epi(
    const float* __restrict__ gpart, const float* __restrict__ dc_in,
    const float* __restrict__ bih, const float* __restrict__ bhh,
    u16* __restrict__ dhac)
{
  const int lin = blockIdx.x * 256 + threadIdx.x;
  const int m = lin >> 10, j = lin & 1023;
  float p4[4] = {0, 0, 0, 0};
  for (int ks = 0; ks < 8; ++ks) {
    const float* gp = gpart + (size_t)ks * 262144 + m * 4096 + j;
    p4[0] += gp[0];
    p4[1] += gp[1024];
    p4[2] += gp[2048];
    p4[3] += gp[3072];
  }
  const float pi = p4[0] + bih[j]        + bhh[j];
  const float pf = p4[1] + bih[1024 + j] + bhh[1024 + j];
  const float pg = p4[2] + bih[2048 + j] + bhh[2048 + j];
  const float po = p4[3] + bih[3072 + j] + bhh[3072 + j];
  const float c2 = sigm(pf) * dc_in[m * 1024 + j] + sigm(pi) * tanh_(pg);
  const float h2 = sigm(po) * tanh_(c2);
  dhac[m * 1280 + j] = f2bf_rne(h2);
}

// ---------------------------------------------------------------------------
// K5 GEMM: proj partial planes = dhac(bf16) @ Wp^T, grid (4 n-tiles, 20 chunks)
// ---------------------------------------------------------------------------
__global__ __launch_bounds__(256) void k5_gemm(
    const u16* __restrict__ dhac, const float* __restrict__ Wp,
    float* __restrict__ proj_p)
{
  const int tid = threadIdx.x;
  const int w = tid >> 6, lane = tid & 63, quad = lane >> 4, l16 = lane & 15;
  const int n = blockIdx.x * 64 + w * 16 + l16, ks = blockIdx.y;
  const int kb0 = ks * 64;
  f32x4 acc[4] = {{0,0,0,0},{0,0,0,0},{0,0,0,0},{0,0,0,0}};
#pragma unroll
  for (int kb = kb0; kb < kb0 + 64; kb += 32) {
    const int k = kb + quad * 8;
    bf16x8 b_h, b_l; split8t(Wp + n * 1280 + k, b_h, b_l);
#pragma unroll
    for (int mt = 0; mt < 4; ++mt) {
      bf16x8 af = ldb(dhac + (mt * 16 + l16) * 1280 + k);
      acc[mt] = mfma16(af, b_h, acc[mt]);
      acc[mt] = mfma16(af, b_l, acc[mt]);
    }
  }
  float* dst = proj_p + (size_t)ks * 16384;
#pragma unroll
  for (int mt = 0; mt < 4; ++mt)
#pragma unroll
    for (int r = 0; r < 4; ++r)
      dst[(mt * 16 + quad * 4 + r) * 256 + n] = acc[mt][r];
}

// ---------------------------------------------------------------------------
// K5 epilogue: blocks 0..63 sum 20 planes + bias -> out; 64..79 stop gates.
// ---------------------------------------------------------------------------
__global__ __launch_bounds__(256) void k5_epi(
    const float* __restrict__ proj_p, const float* __restrict__ bp,
    const u16* __restrict__ dhac, const float* __restrict__ Wg,
    const float* __restrict__ bg, float* __restrict__ out)
{
  const int tid = threadIdx.x;
  if (blockIdx.x < 64) {
    const int m = blockIdx.x;
    float s = bp[tid];
#pragma unroll
    for (int ks = 0; ks < 20; ++ks) s += proj_p[(size_t)ks * 16384 + m * 256 + tid];
    out[m * 256 + tid] = s;
  } else {
    const int w = tid >> 6, lane = tid & 63;
    const int bb = (blockIdx.x - 64) * 4 + w;
    float s = 0.0f;
    for (int k = lane; k < 1280; k += 64) s += bf2f(dhac[bb * 1280 + k]) * Wg[k];
    for (int off = 1; off < 64; off <<= 1) s += __shfl_xor(s, off, 64);
    if (lane == 0) out[16384 + bb] = s + bg[0];
  }
}

extern "C" void kernel_launch(void* const* d_in, const int* in_sizes, int n_in,
                              void* d_out, int out_size, void* d_ws, size_t ws_size,
                              hipStream_t stream)
{
  (void)in_sizes; (void)n_in; (void)out_size; (void)ws_size;
  const float* lf    = (const float*)d_in[0];
  const float* ah0   = (const float*)d_in[1];
  const float* ac0   = (const float*)d_in[2];
  const float* aw    = (const float*)d_in[3];
  const float* awc   = (const float*)d_in[4];
  const float* actx  = (const float*)d_in[5];
  const float* dh0   = (const float*)d_in[6];
  const float* dc0   = (const float*)d_in[7];
  const float* mem   = (const float*)d_in[8];
  const float* pm    = (const float*)d_in[9];
  const float* Wih_a = (const float*)d_in[10];
  const float* Whh_a = (const float*)d_in[11];
  const float* bih_a = (const float*)d_in[12];
  const float* bhh_a = (const float*)d_in[13];
  const float* Wq    = (const float*)d_in[14];
  const float* Wv    = (const float*)d_in[15];
  const float* Wloc  = (const float*)d_in[16];
  const float* Wlfc  = (const float*)d_in[17];
  const float* Wih_d = (const float*)d_in[18];
  const float* Whh_d = (const float*)d_in[19];
  const float* bih_d = (const float*)d_in[20];
  const float* bhh_d = (const float*)d_in[21];
  const float* Wp    = (const float*)d_in[22];
  const float* bp    = (const float*)d_in[23];
  const float* Wg    = (const float*)d_in[24];
  const float* bg    = (const float*)d_in[25];
  const int* msk     = (const int*)d_in[26];

  // ---- workspace layout (fp32 offsets); no memset: every buffer is ----
  // ---- fully written by its producer before any consumer reads it. ----
  float* wsf     = (float*)d_ws;
  float* ga_part = wsf;                    // [8][64][4096] = 2M
  float* gd_part = wsf + 2097152;          // [8][64][4096] = 2M
  float* proj_p  = wsf + 4194304;          // [20][64][256] = 327680
  float* ctx_p   = wsf + 4521984;          // [8][64][256]  = 131072
  float* ctx     = wsf + 4653056;          // [64][256]
  float* ah_f    = wsf + 4669440;          // [64][1024]
  float* pq      = wsf + 4734976;          // [64][128]
  float* e_g     = wsf + 4743168;          // [64][2048]
  u16*  xd       = (u16*)(wsf + 4874240);  // [64][1024] bf16
  u16*  dhac     = xd + 65536;             // [64][1280] bf16
  u16*  w2b      = dhac + 81920;           // [128][64] bf16

  float* out   = (float*)d_out;
  float* out_w = out + 16448;              // after proj(16384) + stop(64)

  k0_prep <<<64, 128, 0, stream>>>(Wloc, Wlfc, w2b);
  k1_gemm <<<dim3(64, 8), 256, 0, stream>>>(lf, actx, ah0, Wih_a, Whh_a, ga_part);
  k1_epi  <<<256, 256, 0, stream>>>(ga_part, ac0, bih_a, bhh_a, ah_f, xd);
  k2a_pq  <<<dim3(8, 64), 256, 0, stream>>>(ah_f, Wq, pq);
  k2_energy<<<dim3(64, 64), 256, 0, stream>>>(aw, awc, pm, Wv, pq, w2b, msk, e_g);
  k3f_ctx <<<dim3(8, 64), 256, 0, stream>>>(e_g, mem, ctx_p, out_w);
  k3s_sum <<<64, 256, 0, stream>>>(ctx_p, ctx, dhac);
  k4_gemm <<<dim3(64, 8), 256, 0, stream>>>(xd, ctx, dh0, Wih_d, Whh_d, gd_part);
  k4_epi  <<<256, 256, 0, stream>>>(gd_part, dc0, bih_d, bhh_d, dhac);
  k5_gemm <<<dim3(4, 20), 256, 0, stream>>>(dhac, Wp, proj_p);
  k5_epi  <<<80, 256, 0, stream>>>(proj_p, bp, dhac, Wg, bg, out);
}